// Round 11
// baseline (491.129 us; speedup 1.0000x reference)
//
#include <hip/hip_runtime.h>

typedef unsigned short u16;
typedef __attribute__((ext_vector_type(8))) short bf16x8;   // 8 bf16 in 4 VGPRs
typedef __attribute__((ext_vector_type(4))) float f32x4;

__device__ __forceinline__ float bf2f(unsigned int u) {
    union { unsigned int i; float f; } c; c.i = u << 16; return c.f;
}
__device__ __forceinline__ unsigned int f2bf(float f) {
    union { float f; unsigned int i; } c; c.f = f;
    unsigned int x = c.i;
    unsigned int r = x + 0x7FFFu + ((x >> 16) & 1u);
    return r >> 16;  // RNE; finite inputs
}

// async global->LDS, 16B per lane, LDS dest = wave-uniform base + lane*16
__device__ __forceinline__ void gld16(const u16* g, u16* l) {
    __builtin_amdgcn_global_load_lds(
        (const __attribute__((address_space(1))) void*)g,
        (__attribute__((address_space(3))) void*)l, 16, 0, 0);
}

// ---- 32x32 weight tile convert+transpose (device helper) ----
__device__ __forceinline__ void wconv_tile(const float* __restrict__ W, u16* __restrict__ Wt,
                                           int K, int N, int bx, int by, int t) {
    __shared__ u16 tile[32][36];
    int k0 = by * 32, n0 = bx * 32;
    int r = t >> 3, c4 = (t & 7) * 4;
    float4 v = *(const float4*)(W + (size_t)(k0 + r) * N + n0 + c4);
    tile[r][c4 + 0] = (u16)f2bf(v.x);
    tile[r][c4 + 1] = (u16)f2bf(v.y);
    tile[r][c4 + 2] = (u16)f2bf(v.z);
    tile[r][c4 + 3] = (u16)f2bf(v.w);
    __syncthreads();
    int n = t >> 3, k4 = (t & 7) * 4;
    u16 a0 = tile[k4 + 0][n], a1 = tile[k4 + 1][n];
    u16 a2 = tile[k4 + 2][n], a3 = tile[k4 + 3][n];
    uint2 st;
    st.x = (unsigned)a0 | ((unsigned)a1 << 16);
    st.y = (unsigned)a2 | ((unsigned)a3 << 16);
    *(uint2*)(Wt + (size_t)(n0 + n) * K + k0 + k4) = st;
}

// ---- prep: weight transposes + packed-pair bias table + LN1 stats, ONE launch ----
__global__ __launch_bounds__(256) void prep_kernel(const float* __restrict__ qkv_w, u16* wq_t,
                                                   const float* __restrict__ proj_w, u16* wp_t,
                                                   const float* __restrict__ fc1_w, u16* w1_t,
                                                   const float* __restrict__ fc2_w, u16* w2_t,
                                                   const float* __restrict__ bias_table,
                                                   unsigned* __restrict__ biasP,
                                                   const float* __restrict__ x,
                                                   float* __restrict__ mu, float* __restrict__ rsig) {
    int id = blockIdx.x, t = threadIdx.x;
    if (id < 768) {
        wconv_tile(qkv_w, wq_t, 512, 1536, id % 48, id / 48, t);
    } else if (id < 1024) {
        int l = id - 768;  wconv_tile(proj_w, wp_t, 512, 512, l % 16, l / 16, t);
    } else if (id < 2048) {
        int l = id - 1024; wconv_tile(fc1_w, w1_t, 512, 2048, l % 64, l / 64, t);
    } else if (id < 3072) {
        int l = id - 2048; wconv_tile(fc2_w, w2_t, 2048, 512, l % 16, l / 16, t);
    } else if (id < 3328) {
        // biasP[h][i] = bf16(bias[i][h]) | bf16(bias[i+1][h])<<16, stride 3970 per h
        int l = id - 3072;
        int h = l >> 4, i = (l & 15) * 256 + t;
        if (i < 3969) {
            unsigned lo = f2bf(bias_table[(size_t)i * 16 + h]);
            unsigned hi = (i + 1 < 3969) ? f2bf(bias_table[(size_t)(i + 1) * 16 + h]) : 0u;
            biasP[(size_t)h * 3970 + i] = lo | (hi << 16);
        }
    } else {
        // LN1 stats: 4 rows per block, one wave each
        int row = (id - 3328) * 4 + (t >> 6);
        int lane = t & 63;
        const float* xr = x + (size_t)row * 512 + lane * 8;
        float4 a = *(const float4*)xr;
        float4 c = *(const float4*)(xr + 4);
        float v[8] = { a.x, a.y, a.z, a.w, c.x, c.y, c.z, c.w };
        float s = 0.f, ss = 0.f;
#pragma unroll
        for (int i = 0; i < 8; ++i) { s += v[i]; ss += v[i] * v[i]; }
#pragma unroll
        for (int off = 32; off; off >>= 1) {
            s  += __shfl_down(s, off);
            ss += __shfl_down(ss, off);
        }
        if (lane == 0) {
            float m = s * (1.0f / 512.0f);
            float var = ss * (1.0f / 512.0f) - m * m;
            mu[row] = m;
            rsig[row] = rsqrtf(var + 1e-5f);
        }
    }
}

// ---- LN row stats for bf16 input (x2) ----
__global__ __launch_bounds__(256) void ln_stats_bf(const u16* __restrict__ xin,
                                                   float* __restrict__ mu, float* __restrict__ rsig) {
    int row = blockIdx.x * 4 + (threadIdx.x >> 6);
    int t = threadIdx.x & 63;
    uint4 u = *(const uint4*)(xin + (size_t)row * 512 + t * 8);
    float v[8];
    v[0]=bf2f(u.x&0xffff); v[1]=bf2f(u.x>>16); v[2]=bf2f(u.y&0xffff); v[3]=bf2f(u.y>>16);
    v[4]=bf2f(u.z&0xffff); v[5]=bf2f(u.z>>16); v[6]=bf2f(u.w&0xffff); v[7]=bf2f(u.w>>16);
    float s = 0.f, ss = 0.f;
#pragma unroll
    for (int i = 0; i < 8; ++i) { s += v[i]; ss += v[i] * v[i]; }
#pragma unroll
    for (int off = 32; off; off >>= 1) {
        s  += __shfl_down(s, off);
        ss += __shfl_down(ss, off);
    }
    if (t == 0) {
        float m = s * (1.0f / 512.0f);
        float var = ss * (1.0f / 512.0f) - m * m;
        mu[row] = m;
        rsig[row] = rsqrtf(var + 1e-5f);
    }
}

// ---- MFMA GEMM. BM = 128 or 64. BN=128, BK=32, 16x16x32 MFMA, fp32 acc.
// B staged via async global_load_lds into [colblock][kseg][col15] layout (conflict-free).
// RES: 0 none, 1 fp32, 2 bf16. COUT: 0 bf16, 1 fp32. SPLIT: qkv 3-way (Q / K / V->VT).
template <int BM, int AIN, int LNA, int ACT, int RES, int COUT, int SPLIT>
__global__ __launch_bounds__(256) void gemm_mfma(const void* __restrict__ A, int lda,
                                                 const float* __restrict__ mu,
                                                 const float* __restrict__ rsig,
                                                 const float* __restrict__ lng,
                                                 const float* __restrict__ lnb,
                                                 const u16* __restrict__ Bt,
                                                 const float* __restrict__ bias,
                                                 const void* __restrict__ res, int ldres,
                                                 void* __restrict__ C, int ldC,
                                                 u16* __restrict__ Ck, u16* __restrict__ Cv,
                                                 int K) {
    constexpr int NI = BM / 32;                 // row frags per wave
    __shared__ u16 As[BM * 56];
    __shared__ u16 Bs[4096];                    // 128 cols x 32 k, cell = cb*64+kseg*16+col15
    int tid = threadIdx.x;
    int bm = blockIdx.y * BM, bn = blockIdx.x * 128;
    int lane = tid & 63, wv = tid >> 6;
    int q = lane >> 4, lr = lane & 15;
    int wr = wv >> 1, wc = wv & 1;
    int sr  = (BM == 128) ? (tid >> 1) : (tid >> 2);
    int skh = (BM == 128) ? ((tid & 1) * 16) : ((tid & 3) * 8);
    constexpr int AE = (BM == 128) ? 16 : 8;

    // async B staging pointers: lane -> (kseg = lane>>4, col15 = lane&15)
    const u16* Bg0 = Bt + (size_t)(bn + wv * 16 + lr) * K + ((lane >> 4) * 8);
    const u16* Bg1 = Bg0 + (size_t)64 * K;
    u16* Bw0 = &Bs[wv * 512];
    u16* Bw1 = &Bs[(wv + 4) * 512];

    u16* Asw = &As[sr * 56 + skh];
    const u16* Apf = &As[(wr * (NI * 16) + lr) * 56 + q * 8];

    float mu_r = 0.f, rs_r = 1.f;
    if (LNA) { mu_r = mu[bm + sr]; rs_r = rsig[bm + sr]; }

    f32x4 acc[NI][4];
#pragma unroll
    for (int i = 0; i < NI; ++i)
#pragma unroll
        for (int j = 0; j < 4; ++j) acc[i][j] = (f32x4){0.f, 0.f, 0.f, 0.f};

    for (int k0 = 0; k0 < K; k0 += 32) {
        u16 av[AE];
        if (AIN == 0) {
            const float* Ag = (const float*)A + (size_t)(bm + sr) * lda + skh + k0;
            float tmp[AE];
#pragma unroll
            for (int c = 0; c < AE / 4; ++c) {
                float4 v = *(const float4*)(Ag + c * 4);
                tmp[c*4+0]=v.x; tmp[c*4+1]=v.y; tmp[c*4+2]=v.z; tmp[c*4+3]=v.w;
            }
            if (LNA) {
#pragma unroll
                for (int c = 0; c < AE / 4; ++c) {
                    float4 g4 = *(const float4*)(lng + k0 + skh + c * 4);
                    float4 b4 = *(const float4*)(lnb + k0 + skh + c * 4);
                    tmp[c*4+0] = (tmp[c*4+0]-mu_r)*rs_r*g4.x + b4.x;
                    tmp[c*4+1] = (tmp[c*4+1]-mu_r)*rs_r*g4.y + b4.y;
                    tmp[c*4+2] = (tmp[c*4+2]-mu_r)*rs_r*g4.z + b4.z;
                    tmp[c*4+3] = (tmp[c*4+3]-mu_r)*rs_r*g4.w + b4.w;
                }
            }
#pragma unroll
            for (int j = 0; j < AE; ++j) av[j] = (u16)f2bf(tmp[j]);
        } else {
            const u16* Ag = (const u16*)A + (size_t)(bm + sr) * lda + skh + k0;
#pragma unroll
            for (int c = 0; c < AE / 8; ++c)
                *(uint4*)(av + c * 8) = *(const uint4*)(Ag + c * 8);
            if (LNA) {
                float tmp[AE];
#pragma unroll
                for (int j = 0; j < AE; ++j) tmp[j] = bf2f((unsigned)av[j]);
#pragma unroll
                for (int c = 0; c < AE / 4; ++c) {
                    float4 g4 = *(const float4*)(lng + k0 + skh + c * 4);
                    float4 b4 = *(const float4*)(lnb + k0 + skh + c * 4);
                    tmp[c*4+0] = (tmp[c*4+0]-mu_r)*rs_r*g4.x + b4.x;
                    tmp[c*4+1] = (tmp[c*4+1]-mu_r)*rs_r*g4.y + b4.y;
                    tmp[c*4+2] = (tmp[c*4+2]-mu_r)*rs_r*g4.z + b4.z;
                    tmp[c*4+3] = (tmp[c*4+3]-mu_r)*rs_r*g4.w + b4.w;
                }
#pragma unroll
                for (int j = 0; j < AE; ++j) av[j] = (u16)f2bf(tmp[j]);
            }
        }
        __syncthreads();
        gld16(Bg0 + k0, Bw0);
        gld16(Bg1 + k0, Bw1);
#pragma unroll
        for (int c = 0; c < AE / 8; ++c)
            *(uint4*)(Asw + c * 8) = *(uint4*)(av + c * 8);
        __syncthreads();    // drains vmcnt (async B) + lgkmcnt (A writes)
        bf16x8 af[NI], bfr[4];
#pragma unroll
        for (int i = 0; i < NI; ++i) af[i] = *(const bf16x8*)(Apf + i * 16 * 56);
#pragma unroll
        for (int j = 0; j < 4; ++j)
            bfr[j] = *(const bf16x8*)&Bs[((wc * 4 + j) * 64 + q * 16 + lr) * 8];
#pragma unroll
        for (int i = 0; i < NI; ++i)
#pragma unroll
            for (int j = 0; j < 4; ++j)
                acc[i][j] = __builtin_amdgcn_mfma_f32_16x16x32_bf16(af[i], bfr[j], acc[i][j], 0, 0, 0);
    }

    float bv[4];
#pragma unroll
    for (int j = 0; j < 4; ++j)
        bv[j] = bias ? bias[bn + wc * 64 + j * 16 + lr] : 0.f;
#pragma unroll
    for (int i = 0; i < NI; ++i) {
#pragma unroll
        for (int j = 0; j < 4; ++j) {
            int col = bn + wc * 64 + j * 16 + lr;
            int row0 = bm + wr * (NI * 16) + i * 16 + q * 4;
            float o[4];
#pragma unroll
            for (int r = 0; r < 4; ++r) {
                float v = acc[i][j][r] + bv[j];
                if (ACT) v = 0.5f * v * (1.0f + erff(v * 0.7071067811865475f));
                if (RES == 1) v += ((const float*)res)[(size_t)(row0 + r) * ldres + col];
                if (RES == 2) v += bf2f((unsigned)((const u16*)res)[(size_t)(row0 + r) * ldres + col]);
                o[r] = v;
            }
            if (SPLIT) {
                if (col < 512) {
#pragma unroll
                    for (int r = 0; r < 4; ++r)
                        ((u16*)C)[(size_t)(row0 + r) * 512 + col] = (u16)f2bf(o[r]);
                } else if (col < 1024) {
#pragma unroll
                    for (int r = 0; r < 4; ++r)
                        Ck[(size_t)(row0 + r) * 512 + col - 512] = (u16)f2bf(o[r]);
                } else {
                    // V -> VT[z][h][d][l], 4 consecutive l => one uint2 store
                    int hh = (col - 1024) >> 5, dd = (col - 1024) & 31;
                    int zz = row0 >> 10, l0 = row0 & 1023;
                    uint2 w;
                    w.x = f2bf(o[0]) | (f2bf(o[1]) << 16);
                    w.y = f2bf(o[2]) | (f2bf(o[3]) << 16);
                    *(uint2*)&Cv[(((size_t)zz * 16 + hh) * 32 + dd) * 1024 + l0] = w;
                }
            } else if (COUT == 0) {
#pragma unroll
                for (int r = 0; r < 4; ++r)
                    ((u16*)C)[(size_t)(row0 + r) * ldC + col] = (u16)f2bf(o[r]);
            } else {
#pragma unroll
                for (int r = 0; r < 4; ++r)
                    ((float*)C)[(size_t)(row0 + r) * ldC + col] = o[r];
            }
        }
    }
}

// ---- Flash attention, transposed-QK formulation. 1D grid 2048, XCD-swizzled. ----
// Q/O in outQ[8192][512] (in-place); K in Kbuf[8192][512]; V in VT[z][h][d][l]; biasP packed pairs.
__global__ __launch_bounds__(256) void attn_mfma(u16* __restrict__ outQ,
                                                 const u16* __restrict__ Kbuf,
                                                 const u16* __restrict__ VT,
                                                 const unsigned* __restrict__ biasPg) {
    __shared__ u16 Ks[64][40];
    __shared__ u16 Vs[32][72];
    __shared__ u16 Ps[4][16][72];
    __shared__ unsigned biascP[3970];
    int tid = threadIdx.x;
    int i = blockIdx.x;
    int hz = (i & 7) * 16 + ((i >> 3) & 15);   // XCD j (=i%8) gets hz in [j*16, j*16+16)
    int qt = i >> 7;
    int h = hz & 15, z = hz >> 4;

    u16* Qz = outQ + (size_t)z * 1024 * 512;
    const u16* Kz = Kbuf + (size_t)z * 1024 * 512;
    const u16* Vz = VT + ((size_t)z * 16 + h) * 32 * 1024;

    for (int ii = tid; ii < 3969; ii += 256) biascP[ii] = biasPg[(size_t)h * 3970 + ii];

    int lane = tid & 63, wv = tid >> 6;
    int q = lane >> 4, m = lane & 15;

    int l = qt * 64 + wv * 16 + m;              // this lane's query row
    bf16x8 qf = *(const bf16x8*)(Qz + (size_t)l * 512 + h * 32 + q * 8);
    int lidx = (l >> 5) * 63 + (l & 31) + 1984;

    const float scale = 0.17677669529663687f;
    float lsum = 0.f;
    f32x4 acco[2] = { (f32x4){0.f,0.f,0.f,0.f}, (f32x4){0.f,0.f,0.f,0.f} };

    int skey = tid >> 2, sdh = (tid & 3) * 8;   // K staging
    int svd = tid >> 3, svk = (tid & 7) * 8;    // V staging

    uint4 kreg = *(const uint4*)(Kz + (size_t)skey * 512 + h * 32 + sdh);
    uint4 vreg = *(const uint4*)(Vz + (size_t)svd * 1024 + svk);

    for (int kt = 0; kt < 16; ++kt) {
        __syncthreads();
        *(uint4*)&Ks[skey][sdh] = kreg;
        *(uint4*)&Vs[svd][svk] = vreg;
        if (kt < 15) {
            kreg = *(const uint4*)(Kz + (size_t)((kt + 1) * 64 + skey) * 512 + h * 32 + sdh);
            vreg = *(const uint4*)(Vz + (size_t)svd * 1024 + (kt + 1) * 64 + svk);
        }
        __syncthreads();

        // S^T = K @ Q^T : lane (q,m) holds S[key = kt*64 + t*16 + q*4 + r][query = m]
        f32x4 st[4];
#pragma unroll
        for (int t = 0; t < 4; ++t) {
            bf16x8 kf = *(const bf16x8*)&Ks[t * 16 + m][q * 8];
            st[t] = __builtin_amdgcn_mfma_f32_16x16x32_bf16(
                kf, qf, (f32x4){0.f,0.f,0.f,0.f}, 0, 0, 0);
        }
#pragma unroll
        for (int t = 0; t < 4; ++t) {
            int key0 = kt * 64 + t * 16 + q * 4;
            int kidx0 = (key0 >> 5) * 63 + (key0 & 31);
            int base = lidx - kidx0 - 3;        // = idx(r=3); idx(r) = lidx - kidx0 - r
            unsigned ba = biascP[base];         // lo=idx3, hi=idx2
            unsigned bb = biascP[base + 2];     // lo=idx1, hi=idx0
            float p0 = __expf(fmaf(st[t][0], scale, bf2f(bb >> 16)));
            float p1 = __expf(fmaf(st[t][1], scale, bf2f(bb & 0xffff)));
            float p2 = __expf(fmaf(st[t][2], scale, bf2f(ba >> 16)));
            float p3 = __expf(fmaf(st[t][3], scale, bf2f(ba & 0xffff)));
            lsum += p0 + p1 + p2 + p3;          // this lane's keys, query m; reduce at end
            uint2 w;
            w.x = f2bf(p0) | (f2bf(p1) << 16);
            w.y = f2bf(p2) | (f2bf(p3) << 16);
            *(uint2*)&Ps[wv][m][t * 16 + q * 4] = w;   // P^T already in A-layout rows
        }
        asm volatile("s_waitcnt lgkmcnt(0)" ::: "memory");  // wave-local Ps drain
#pragma unroll
        for (int c = 0; c < 2; ++c) {
            bf16x8 pf = *(const bf16x8*)&Ps[wv][m][c * 32 + q * 8];
#pragma unroll
            for (int dt = 0; dt < 2; ++dt) {
                bf16x8 vf = *(const bf16x8*)&Vs[dt * 16 + m][c * 32 + q * 8];
                acco[dt] = __builtin_amdgcn_mfma_f32_16x16x32_bf16(pf, vf, acco[dt], 0, 0, 0);
            }
        }
    }
    // total l per query m (sum over q-lanes), then redistribute to C-layout rows
    lsum += __shfl_xor(lsum, 16);
    lsum += __shfl_xor(lsum, 32);
#pragma unroll
    for (int r = 0; r < 4; ++r) {
        float inv = 1.0f / __shfl(lsum, q * 4 + r);
        int lq = qt * 64 + wv * 16 + q * 4 + r;
#pragma unroll
        for (int dt = 0; dt < 2; ++dt)
            Qz[(size_t)lq * 512 + h * 32 + dt * 16 + m] = (u16)f2bf(acco[dt][r] * inv);
    }
}

extern "C" void kernel_launch(void* const* d_in, const int* in_sizes, int n_in,
                              void* d_out, int out_size, void* d_ws, size_t ws_size,
                              hipStream_t stream) {
    const float* x          = (const float*)d_in[0];
    const float* bias_table = (const float*)d_in[2];
    const float* qkv_w      = (const float*)d_in[3];
    const float* qkv_b      = (const float*)d_in[4];
    const float* proj_w     = (const float*)d_in[5];
    const float* proj_b     = (const float*)d_in[6];
    const float* n1g        = (const float*)d_in[7];
    const float* n1b        = (const float*)d_in[8];
    const float* n2g        = (const float*)d_in[9];
    const float* n2b        = (const float*)d_in[10];
    const float* fc1_w      = (const float*)d_in[11];
    const float* fc1_b      = (const float*)d_in[12];
    const float* fc2_w      = (const float*)d_in[13];
    const float* fc2_b      = (const float*)d_in[14];
    float* out = (float*)d_out;

    // ws (u16 elems), total ~30.2 MB: wq_t@0, wp_t@786432, w1_t@1048576, w2_t@2097152,
    //  x2h@3145728, Kbuf@7340032, VT@11534336 (hid overlays Kbuf+VT), biasP@15728640 (u32),
    //  stats after.
    u16* ws16  = (u16*)d_ws;
    u16* wq_t  = ws16;
    u16* wp_t  = ws16 + 786432;
    u16* w1_t  = ws16 + 1048576;
    u16* w2_t  = ws16 + 2097152;
    u16* x2h   = ws16 + 3145728;
    u16* Kbuf  = ws16 + 7340032;
    u16* VT    = ws16 + 11534336;
    u16* hid   = Kbuf;                          // 8.39M u16, overlays Kbuf+VT after attn
    unsigned* biasP = (unsigned*)(ws16 + 15728640);
    float* mu1 = (float*)((char*)biasP + 16 * 3970 * 4);
    float* rs1 = mu1 + 8192;
    float* mu2 = rs1 + 8192;
    float* rs2 = mu2 + 8192;
    u16* outQ  = (u16*)d_out;                   // bf16 Q/O scratch inside fp32 out buffer

    // prep (weights, biasP) + LN1 stats, one launch
    prep_kernel<<<5376, 256, 0, stream>>>(qkv_w, wq_t, proj_w, wp_t, fc1_w, w1_t,
                                          fc2_w, w2_t, bias_table, biasP, x, mu1, rs1);
    // qkv = LN1(x) @ qkv_w + qkv_b, split Q->outQ, K->Kbuf, V->VT (transposed store)
    gemm_mfma<128, 0, 1, 0, 0, 0, 1><<<dim3(12, 64), 256, 0, stream>>>(
        x, 512, mu1, rs1, n1g, n1b, wq_t, qkv_b, nullptr, 0, outQ, 512, Kbuf, VT, 512);
    attn_mfma<<<2048, 256, 0, stream>>>(outQ, Kbuf, VT, biasP);
    // x2(bf16) = attnO @ proj_w + proj_b + x
    gemm_mfma<64, 1, 0, 0, 1, 0, 0><<<dim3(4, 128), 256, 0, stream>>>(
        outQ, 512, nullptr, nullptr, nullptr, nullptr, wp_t, proj_b, x, 512,
        x2h, 512, nullptr, nullptr, 512);
    ln_stats_bf<<<2048, 256, 0, stream>>>(x2h, mu2, rs2);
    for (int half = 0; half < 2; ++half) {
        size_t ro = (size_t)half * 4096;
        // hid = gelu(LN2(x2) @ fc1_w + fc1_b)
        gemm_mfma<128, 1, 1, 1, 0, 0, 0><<<dim3(16, 32), 256, 0, stream>>>(
            x2h + ro * 512, 512, mu2 + ro, rs2 + ro, n2g, n2b, w1_t, fc1_b,
            nullptr, 0, hid, 2048, nullptr, nullptr, 512);
        // out(fp32) = hid @ fc2_w + fc2_b + x2
        gemm_mfma<64, 1, 0, 0, 2, 1, 0><<<dim3(4, 64), 256, 0, stream>>>(
            hid, 2048, nullptr, nullptr, nullptr, nullptr, w2_t, fc2_b,
            x2h + ro * 512, 512, out + ro * 512, 512, nullptr, nullptr, 2048);
    }
}